// Round 7
// baseline (427.796 us; speedup 1.0000x reference)
//
#include <hip/hip_runtime.h>

// GraphAttentionLayer: B=16, N=2048, F_IN=256, H=128 (fp32 in/out, adj int32)
//  k_wh  : MFMA bf16x3-split GEMM wh = X@W^T + bW; fused src/dst dots
//          (log2e + ba folded); writes wh in MFMA B-FRAGMENT order.
//  k_attn: producer/consumer wave-specialized fused pack+attention.
//          512 threads = 8 waves: waves 0-3 COMPUTE (ds_read/VALU/MFMA only,
//          no HBM in their vmcnt queue), waves 4-7 PRODUCE (whF->whS staging
//          2 chunks ahead; adj->ballot->maskB 6+ chunks ahead in 8-chunk
//          groups). R6 ran pack(43us HBM) THEN loop(46us LDS) sequentially
//          since all blocks are co-resident; specialization overlaps them ->
//          loop hides under the adj stream. Mask = raw-ballot layout:
//          maskB[bank][2k+hi][row], bit_j = ballot_{j&3} >> (8(C&3)+2q+(j>>2)).
//          vmcnt ordering: whF loads issued BEFORE adj each chunk -> whS
//          write next chunk waits only whF (adj is NEWER, needn't drain).

#define BDIM 16
#define NDIM 2048
#define FIN 256
#define HDIM 128
#define LOG2E 1.4426950408889634f

typedef short short8 __attribute__((ext_vector_type(8)));
typedef float floatx4 __attribute__((ext_vector_type(4)));
typedef int intx4 __attribute__((ext_vector_type(4)));

__device__ __forceinline__ unsigned short f2bf(float x) {
    unsigned int u = __float_as_uint(x);
    unsigned int r = (u + 0x7fffu + ((u >> 16) & 1u)) >> 16;  // RNE
    return (unsigned short)r;
}
__device__ __forceinline__ float bf2f(unsigned short s) {
    return __uint_as_float(((unsigned int)s) << 16);
}
__device__ __forceinline__ intx4 ldnt(const int* p) {
    return __builtin_nontemporal_load(reinterpret_cast<const intx4*>(p));
}

// ---------------- Kernel 1: wh via MFMA (bf16 hi/lo split) ----------------
// 64 rows x 128 h per block; 4 waves = 4 m-tiles of 16; K in panels of 64.
__global__ __launch_bounds__(256) void k_wh(const float* __restrict__ X,
                                            const float* __restrict__ W,
                                            const float* __restrict__ bW,
                                            const float* __restrict__ a,
                                            const float* __restrict__ ba_p,
                                            float* __restrict__ src,
                                            float* __restrict__ dst,
                                            unsigned short* __restrict__ whF) {
    __shared__ short lds[27648];                    // 54 KB
    short (*ah)[72] = (short(*)[72])lds;
    short (*al)[72] = (short(*)[72])(lds + 4608);
    short (*bh)[72] = (short(*)[72])(lds + 9216);
    short (*bl)[72] = (short(*)[72])(lds + 18432);
    short (*tb)[72] = (short(*)[72])lds;            // epilogue alias [128][72]

    const int tid = threadIdx.x;
    const long row0 = (long)blockIdx.x * 64;
    const int w = tid >> 6, lane = tid & 63;
    const int lm = lane & 15, q = lane >> 4;
    const float ba0 = ba_p[0];

    float a1v[8], a2v[8], bwv[8];
    #pragma unroll
    for (int nt = 0; nt < 8; nt++) {
        a1v[nt] = a[nt * 16 + lm];
        a2v[nt] = a[HDIM + nt * 16 + lm];
        bwv[nt] = bW[nt * 16 + lm];
    }

    floatx4 acc[8];
    #pragma unroll
    for (int nt = 0; nt < 8; nt++) acc[nt] = (floatx4){0.f, 0.f, 0.f, 0.f};

    for (int k0 = 0; k0 < FIN; k0 += 64) {
        #pragma unroll
        for (int u = 0; u < 4; u++) {
            int idx = tid + u * 256;
            int r = idx >> 4, fc = (idx & 15) * 4;
            float4 v = *reinterpret_cast<const float4*>(X + (row0 + r) * FIN + k0 + fc);
            union { unsigned short s[4]; uint2 u2; } ph, pl;
            ph.s[0] = f2bf(v.x); pl.s[0] = f2bf(v.x - bf2f(ph.s[0]));
            ph.s[1] = f2bf(v.y); pl.s[1] = f2bf(v.y - bf2f(ph.s[1]));
            ph.s[2] = f2bf(v.z); pl.s[2] = f2bf(v.z - bf2f(ph.s[2]));
            ph.s[3] = f2bf(v.w); pl.s[3] = f2bf(v.w - bf2f(ph.s[3]));
            *reinterpret_cast<uint2*>(&ah[r][fc]) = ph.u2;
            *reinterpret_cast<uint2*>(&al[r][fc]) = pl.u2;
        }
        #pragma unroll
        for (int u = 0; u < 8; u++) {
            int idx = tid + u * 256;
            int hh = idx >> 4, fc = (idx & 15) * 4;
            float4 v = *reinterpret_cast<const float4*>(W + hh * FIN + k0 + fc);
            union { unsigned short s[4]; uint2 u2; } ph, pl;
            ph.s[0] = f2bf(v.x); pl.s[0] = f2bf(v.x - bf2f(ph.s[0]));
            ph.s[1] = f2bf(v.y); pl.s[1] = f2bf(v.y - bf2f(ph.s[1]));
            ph.s[2] = f2bf(v.z); pl.s[2] = f2bf(v.z - bf2f(ph.s[2]));
            ph.s[3] = f2bf(v.w); pl.s[3] = f2bf(v.w - bf2f(ph.s[3]));
            *reinterpret_cast<uint2*>(&bh[hh][fc]) = ph.u2;
            *reinterpret_cast<uint2*>(&bl[hh][fc]) = pl.u2;
        }
        __syncthreads();
        #pragma unroll
        for (int ks = 0; ks < 64; ks += 32) {
            short8 afh = *reinterpret_cast<const short8*>(&ah[w * 16 + lm][ks + q * 8]);
            short8 afl = *reinterpret_cast<const short8*>(&al[w * 16 + lm][ks + q * 8]);
            #pragma unroll
            for (int nt = 0; nt < 8; nt++) {
                short8 bfh = *reinterpret_cast<const short8*>(&bh[nt * 16 + lm][ks + q * 8]);
                short8 bfl = *reinterpret_cast<const short8*>(&bl[nt * 16 + lm][ks + q * 8]);
                acc[nt] = __builtin_amdgcn_mfma_f32_16x16x32_bf16(afh, bfh, acc[nt], 0, 0, 0);
                acc[nt] = __builtin_amdgcn_mfma_f32_16x16x32_bf16(afh, bfl, acc[nt], 0, 0, 0);
                acc[nt] = __builtin_amdgcn_mfma_f32_16x16x32_bf16(afl, bfh, acc[nt], 0, 0, 0);
            }
        }
        __syncthreads();
    }

    // epilogue: bias, src/dst dots, transpose via LDS -> B-fragment layout
    float s1[4] = {0.f, 0.f, 0.f, 0.f}, s2[4] = {0.f, 0.f, 0.f, 0.f};
    #pragma unroll
    for (int nt = 0; nt < 8; nt++) {
        #pragma unroll
        for (int r = 0; r < 4; r++) {
            float v = acc[nt][r] + bwv[nt];
            s1[r] += v * a1v[nt];
            s2[r] += v * a2v[nt];
            tb[nt * 16 + lm][w * 16 + q * 4 + r] = f2bf(v);   // tb[h][jrel]
        }
    }
    #pragma unroll
    for (int r = 0; r < 4; r++) {
        #pragma unroll
        for (int o = 1; o < 16; o <<= 1) {
            s1[r] += __shfl_xor(s1[r], o);
            s2[r] += __shfl_xor(s2[r], o);
        }
    }
    if (lm == 0) {
        #pragma unroll
        for (int r = 0; r < 4; r++) {
            long row = row0 + w * 16 + q * 4 + r;
            src[row] = (s1[r] + ba0) * LOG2E;   // fold bias-a + log2e (exp -> exp2)
            dst[row] = s2[r] * LOG2E;
        }
    }
    __syncthreads();
    // whF[b][jc][ht][l][e], frag = 512 shorts; block covers jc0..jc0+1
    const int b = (int)(row0 >> 11);
    const int jc0 = (int)((row0 & 2047) >> 5);
    const int f = tid >> 4;          // 0..15: jcrel = f>>3, ht = f&7
    const int sub = tid & 15;
    const int jcrel = f >> 3, ht = f & 7;
    const size_t fbase = (((size_t)b * 64 + jc0 + jcrel) * 8 + ht) * 512;
    #pragma unroll
    for (int i = 0; i < 4; i++) {
        int l = sub * 4 + i;
        uint4 v = *reinterpret_cast<const uint4*>(&tb[ht * 16 + (l & 15)][jcrel * 32 + (l >> 4) * 8]);
        *reinterpret_cast<uint4*>(whF + fbase + l * 8) = v;
    }
}

// ---------------- Kernel 2: wave-specialized pack + MFMA attention --------
// 512 blocks (XCD-swizzled) x 512 threads (8 waves).
// Waves 0-3: compute. Wave cw owns i-rows i0+cw*16..+15 x all 128 h.
// Waves 4-7: produce. Wave (cw=wave-4) stages whS bytes [cw*2KB) and packs
//            adj rows cw*16..+15.
// Mask layout: maskB[bank g&1][2k+hi][row]; for chunk T (C=T&7):
//   bit_j = ballot_{j&3} >> (8*(C&3) + 2q + (j>>2)), hi = (C&4)!=0.

#define MD_PRE(PW1, BK, HI)                                                    \
    do {                                                                       \
        md[PW1][0] = maskB[BK][0 + (HI)][wrow];                                \
        md[PW1][1] = maskB[BK][2 + (HI)][wrow];                                \
        md[PW1][2] = maskB[BK][4 + (HI)][wrow];                                \
        md[PW1][3] = maskB[BK][6 + (HI)][wrow];                                \
    } while (0)

#define ADJ_ISSUE(GNEXT, H)                                                    \
    do {                                                                       \
        _Pragma("unroll")                                                      \
        for (int r = 0; r < 8; r++) {                                          \
            const int* ap = adj +                                              \
                (size_t)(rowbase + cw * 16 + (H) * 8 + r) * NDIM +             \
                (GNEXT) * 256 + lane * 4;                                      \
            av[r] = ldnt(ap);                                                  \
        }                                                                      \
    } while (0)

#define ADJ_BALLOT(GNEXT, H)                                                   \
    do {                                                                       \
        _Pragma("unroll")                                                      \
        for (int r = 0; r < 8; r++) {                                          \
            unsigned long long b0 = __ballot(av[r][0] != 0);                   \
            unsigned long long b1 = __ballot(av[r][1] != 0);                   \
            unsigned long long b2 = __ballot(av[r][2] != 0);                   \
            unsigned long long b3 = __ballot(av[r][3] != 0);                   \
            if (lane < 8) {                                                    \
                unsigned long long bb = (lane < 2) ? b0                        \
                                        : (lane < 4) ? b1                      \
                                        : (lane < 6) ? b2 : b3;                \
                unsigned wv = (lane & 1) ? (unsigned)(bb >> 32) : (unsigned)bb;\
                maskB[(GNEXT) & 1][lane][cw * 16 + (H) * 8 + r] = wv;          \
            }                                                                  \
        }                                                                      \
    } while (0)

// Compute-wave chunk C (literal 0..7), T = g8 + C.
#define CHC(C)                                                                 \
    do {                                                                       \
        constexpr int PW = (C) & 1;                                            \
        const int T = g8 + (C);                                                \
        if (!(g8 == 56 && (C) == 7)) { /* prefetch T+1 */                      \
            const float* dp = dstp + (T + 1) * 32;                             \
            d[PW ^ 1][0] = *reinterpret_cast<const floatx4*>(dp);              \
            d[PW ^ 1][1] = *reinterpret_cast<const floatx4*>(dp + 4);          \
            if ((C) < 7) {                                                     \
                MD_PRE(PW ^ 1, (g8 >> 3) & 1, (((C) + 1) & 4) ? 1 : 0);        \
            } else {                                                           \
                MD_PRE(PW ^ 1, ((g8 >> 3) + 1) & 1, 0);                        \
            }                                                                  \
        }                                                                      \
        const int base = 8 * ((C) & 3) + 2 * q;                                \
        short8 af;                                                             \
        _Pragma("unroll")                                                      \
        for (int j = 0; j < 8; j++) {                                          \
            float x = si + d[PW][j >> 2][j & 3];                               \
            x = fmaxf(x, 0.01f * x);            /* leaky, scale-invariant */   \
            float e2 = __builtin_amdgcn_exp2f(x);                              \
            unsigned bit = (md[PW][j & 3] >> (base + (j >> 2))) & 1u;          \
            float wgt = bit ? e2 : 0.f;                                        \
            lpart += wgt;                                                      \
            af[j] = (short)f2bf(wgt);                                          \
        }                                                                      \
        _Pragma("unroll")                                                      \
        for (int hj = 0; hj < 8; hj++) {                                       \
            short8 fb = *reinterpret_cast<const short8*>(                      \
                &whS[PW][hj * 512 + lane * 8]);                                \
            acc[hj] = __builtin_amdgcn_mfma_f32_16x16x32_bf16(af, fb,          \
                                                              acc[hj], 0, 0, 0); \
        }                                                                      \
    } while (0)

// Producer-wave chunk C (literal 0..7), T = g8 + C.
// whF loads for T+2 issued BEFORE adj loads -> whS write (next chunk) only
// waits for whF (vmcnt in-order: newer adj needn't drain).
#define CHP(C)                                                                 \
    do {                                                                       \
        constexpr int PW = (C) & 1;                                            \
        const int T = g8 + (C);                                                \
        if (T + 2 < 64) { /* issue whF chunk T+2 -> sr[PW] */                  \
            const unsigned short* gp = gsrc + (size_t)(T + 2) * 4096;          \
            sr[PW][0] = *reinterpret_cast<const short8*>(gp);                  \
            sr[PW][1] = *reinterpret_cast<const short8*>(gp + 512);            \
        }                                                                      \
        if ((C) == 0 && g8 < 56) ADJ_ISSUE((g8 >> 3) + 1, 0);                  \
        if ((C) == 3 && g8 < 56) {                                             \
            ADJ_BALLOT((g8 >> 3) + 1, 0);                                      \
            ADJ_ISSUE((g8 >> 3) + 1, 1);                                       \
        }                                                                      \
        if ((C) == 6 && g8 < 56) ADJ_BALLOT((g8 >> 3) + 1, 1);                 \
        if (T + 1 < 64) { /* write chunk T+1 (issued at T-1) */                \
            *reinterpret_cast<short8*>(&whS[PW ^ 1][pofs]) = sr[PW ^ 1][0];    \
            *reinterpret_cast<short8*>(&whS[PW ^ 1][pofs + 512]) = sr[PW ^ 1][1]; \
        }                                                                      \
    } while (0)

#define ITER(C)                                                                \
    do {                                                                       \
        if (wave < 4) { CHC(C); } else { CHP(C); }                             \
        __syncthreads();                                                       \
    } while (0)

__global__ __launch_bounds__(512) void k_attn(const int* __restrict__ adj,
                                              const unsigned short* __restrict__ whF,
                                              const float* __restrict__ src,
                                              const float* __restrict__ dst,
                                              float* __restrict__ out) {
    __shared__ short whS[2][4096];      // 16 KB: staged whF chunk dbuf
    __shared__ unsigned maskB[2][8][64]; // 4 KB: raw-ballot mask dbuf
    __shared__ float lred[64];
    __shared__ float linv_s[64];

    const int tid = threadIdx.x;
    // XCD swizzle: 512 blocks, 8 XCDs -> XCD k gets a contiguous 64-block
    // chunk = batches 2k,2k+1. whF working set/XCD: 1 MB (L2-resident).
    const int bid = ((int)blockIdx.x & 7) * 64 + ((int)blockIdx.x >> 3);
    const int b = bid >> 5;                   // 32 i-tiles per batch
    const int i0 = (bid & 31) * 64;
    const int wave = tid >> 6, lane = tid & 63;
    const int cw = wave & 3;                  // compute-wave id == producer id
    const int lm = lane & 15, q = lane >> 4;
    const int wrow = cw * 16 + lm;            // local i-row (compute waves)
    const int rowbase = b * NDIM + i0;

    const float si = src[rowbase + wrow];     // includes ba and log2e scale
    const float* dstp = dst + b * NDIM + q * 8;
    // producer staging: chunk = 4096 shorts; producer cw covers [cw*1024,+1024)
    const unsigned short* gsrc =
        whF + (size_t)b * 64 * 8 * 512 + cw * 1024 + lane * 8;
    const int pofs = cw * 1024 + lane * 8;

    floatx4 acc[8];
    #pragma unroll
    for (int hj = 0; hj < 8; hj++) acc[hj] = (floatx4){0.f, 0.f, 0.f, 0.f};
    float lpart = 0.f;

    unsigned md[2][4];      // ballot dwords dbuf (compute)
    floatx4 d[2][2];        // dst dbuf (compute, L1-hot)
    short8 sr[2][2];        // whF reg staging dbuf (producer)
    intx4 av[8];            // adj in-flight rows (producer)

    if (wave >= 4) {
        // prologue (producers): stage chunk 0, hold chunk 1, pack group 0
        short8 p0 = *reinterpret_cast<const short8*>(gsrc);
        short8 p1 = *reinterpret_cast<const short8*>(gsrc + 512);
        *reinterpret_cast<short8*>(&whS[0][pofs]) = p0;
        *reinterpret_cast<short8*>(&whS[0][pofs + 512]) = p1;
        sr[1][0] = *reinterpret_cast<const short8*>(gsrc + 4096);
        sr[1][1] = *reinterpret_cast<const short8*>(gsrc + 4096 + 512);
        ADJ_ISSUE(0, 0);
        ADJ_BALLOT(0, 0);
        ADJ_ISSUE(0, 1);
        ADJ_BALLOT(0, 1);
    } else {
        d[0][0] = *reinterpret_cast<const floatx4*>(dstp);
        d[0][1] = *reinterpret_cast<const floatx4*>(dstp + 4);
    }
    __syncthreads();
    if (wave < 4) MD_PRE(0, 0, 0);   // chunk 0: bank 0, hi 0

    for (int g8 = 0; g8 < 64; g8 += 8) {
        ITER(0); ITER(1); ITER(2); ITER(3);
        ITER(4); ITER(5); ITER(6); ITER(7);
    }

    // denominator: combine the 4 q-slices of each row (compute waves)
    lpart += __shfl_xor(lpart, 16);
    lpart += __shfl_xor(lpart, 32);
    if (wave < 4 && q == 0) lred[cw * 16 + lm] = lpart;
    __syncthreads();
    if (tid < 64) {
        float l = lred[tid];
        linv_s[tid] = l > 0.f ? 1.f / l : 0.f;
    }
    __syncthreads();

    // epilogue: scale 1/l, ELU, store (C/D: col=lm -> h, row=q*4+r -> i)
    if (wave < 4) {
        #pragma unroll
        for (int r = 0; r < 4; r++) {
            int il = cw * 16 + q * 4 + r;
            float li = linv_s[il];
            size_t obase = ((size_t)(rowbase + il)) * HDIM + lm;
            #pragma unroll
            for (int hj = 0; hj < 8; hj++) {
                float x = acc[hj][r] * li;
                x = x > 0.f ? x : (__expf(x) - 1.f);
                out[obase + hj * 16] = x;
            }
        }
    }
}

extern "C" void kernel_launch(void* const* d_in, const int* in_sizes, int n_in,
                              void* d_out, int out_size, void* d_ws, size_t ws_size,
                              hipStream_t stream) {
    const float* X  = (const float*)d_in[0];   // [16,2048,256]
    const int* adj  = (const int*)d_in[1];     // [16,2048,2048]
    const float* W  = (const float*)d_in[2];   // [128,256]
    const float* bW = (const float*)d_in[3];   // [128]
    const float* a  = (const float*)d_in[4];   // [1,256]
    const float* ba = (const float*)d_in[5];   // [1]
    float* out = (float*)d_out;                // [16,2048,128]

    float* srcv = (float*)d_ws;                                    // B*N
    float* dstv = srcv + BDIM * NDIM;                              // B*N
    unsigned short* whF = (unsigned short*)(dstv + BDIM * NDIM);   // 8.4 MB bf16 frag-order

    k_wh<<<BDIM * NDIM / 64, 256, 0, stream>>>(X, W, bW, a, ba, srcv, dstv, whF);
    k_attn<<<BDIM * (NDIM / 64), 512, 0, stream>>>(adj, whF, srcv, dstv, out);
}

// Round 8
// 413.716 us; speedup vs baseline: 1.0340x; 1.0340x over previous
//
#include <hip/hip_runtime.h>

// GraphAttentionLayer: B=16, N=2048, F_IN=256, H=128 (fp32 in/out, adj int32)
//  k_wh  : MFMA bf16x3-split GEMM wh = X@W^T + bW; fused src/dst dots
//          (log2e + ba folded); writes wh in MFMA B-FRAGMENT order.
//  k_attn: fine-grained fused pack+attention, 256 thr / 4 waves (R7's
//          4+4 wave specialization regressed: halved compute TLP/SIMD and
//          the barrier coupled producer stalls into compute; merged here).
//          Per 8-chunk group, EACH wave: issue 8 adj rows at C==0 (H0) and
//          C==3 (H1); ballot at C==3/C==6 (3-chunk distance ~1500cy > 900cy
//          HBM; counted vmcnt -- 6 newer whF loads stay in flight). Mask =
//          R7's raw-ballot layout maskB[bank][word][row] (4KB, verified):
//          bit_j of chunk C = ballot_{j&3} >> (8(C&3)+2q+(j>>2)), word
//          2(j&3)+(C>=4). whF chunk staged in LDS dbuf (write-late). adj
//          read once device-wide, interleaved 1:1 with MFMA (AITER pattern).

#define BDIM 16
#define NDIM 2048
#define FIN 256
#define HDIM 128
#define LOG2E 1.4426950408889634f

typedef short short8 __attribute__((ext_vector_type(8)));
typedef float floatx4 __attribute__((ext_vector_type(4)));
typedef int intx4 __attribute__((ext_vector_type(4)));

__device__ __forceinline__ unsigned short f2bf(float x) {
    unsigned int u = __float_as_uint(x);
    unsigned int r = (u + 0x7fffu + ((u >> 16) & 1u)) >> 16;  // RNE
    return (unsigned short)r;
}
__device__ __forceinline__ float bf2f(unsigned short s) {
    return __uint_as_float(((unsigned int)s) << 16);
}
__device__ __forceinline__ intx4 ldnt(const int* p) {
    return __builtin_nontemporal_load(reinterpret_cast<const intx4*>(p));
}

// ---------------- Kernel 1: wh via MFMA (bf16 hi/lo split) ----------------
// 64 rows x 128 h per block; 4 waves = 4 m-tiles of 16; K in panels of 64.
__global__ __launch_bounds__(256) void k_wh(const float* __restrict__ X,
                                            const float* __restrict__ W,
                                            const float* __restrict__ bW,
                                            const float* __restrict__ a,
                                            const float* __restrict__ ba_p,
                                            float* __restrict__ src,
                                            float* __restrict__ dst,
                                            unsigned short* __restrict__ whF) {
    __shared__ short lds[27648];                    // 54 KB
    short (*ah)[72] = (short(*)[72])lds;
    short (*al)[72] = (short(*)[72])(lds + 4608);
    short (*bh)[72] = (short(*)[72])(lds + 9216);
    short (*bl)[72] = (short(*)[72])(lds + 18432);
    short (*tb)[72] = (short(*)[72])lds;            // epilogue alias [128][72]

    const int tid = threadIdx.x;
    const long row0 = (long)blockIdx.x * 64;
    const int w = tid >> 6, lane = tid & 63;
    const int lm = lane & 15, q = lane >> 4;
    const float ba0 = ba_p[0];

    float a1v[8], a2v[8], bwv[8];
    #pragma unroll
    for (int nt = 0; nt < 8; nt++) {
        a1v[nt] = a[nt * 16 + lm];
        a2v[nt] = a[HDIM + nt * 16 + lm];
        bwv[nt] = bW[nt * 16 + lm];
    }

    floatx4 acc[8];
    #pragma unroll
    for (int nt = 0; nt < 8; nt++) acc[nt] = (floatx4){0.f, 0.f, 0.f, 0.f};

    for (int k0 = 0; k0 < FIN; k0 += 64) {
        #pragma unroll
        for (int u = 0; u < 4; u++) {
            int idx = tid + u * 256;
            int r = idx >> 4, fc = (idx & 15) * 4;
            float4 v = *reinterpret_cast<const float4*>(X + (row0 + r) * FIN + k0 + fc);
            union { unsigned short s[4]; uint2 u2; } ph, pl;
            ph.s[0] = f2bf(v.x); pl.s[0] = f2bf(v.x - bf2f(ph.s[0]));
            ph.s[1] = f2bf(v.y); pl.s[1] = f2bf(v.y - bf2f(ph.s[1]));
            ph.s[2] = f2bf(v.z); pl.s[2] = f2bf(v.z - bf2f(ph.s[2]));
            ph.s[3] = f2bf(v.w); pl.s[3] = f2bf(v.w - bf2f(ph.s[3]));
            *reinterpret_cast<uint2*>(&ah[r][fc]) = ph.u2;
            *reinterpret_cast<uint2*>(&al[r][fc]) = pl.u2;
        }
        #pragma unroll
        for (int u = 0; u < 8; u++) {
            int idx = tid + u * 256;
            int hh = idx >> 4, fc = (idx & 15) * 4;
            float4 v = *reinterpret_cast<const float4*>(W + hh * FIN + k0 + fc);
            union { unsigned short s[4]; uint2 u2; } ph, pl;
            ph.s[0] = f2bf(v.x); pl.s[0] = f2bf(v.x - bf2f(ph.s[0]));
            ph.s[1] = f2bf(v.y); pl.s[1] = f2bf(v.y - bf2f(ph.s[1]));
            ph.s[2] = f2bf(v.z); pl.s[2] = f2bf(v.z - bf2f(ph.s[2]));
            ph.s[3] = f2bf(v.w); pl.s[3] = f2bf(v.w - bf2f(ph.s[3]));
            *reinterpret_cast<uint2*>(&bh[hh][fc]) = ph.u2;
            *reinterpret_cast<uint2*>(&bl[hh][fc]) = pl.u2;
        }
        __syncthreads();
        #pragma unroll
        for (int ks = 0; ks < 64; ks += 32) {
            short8 afh = *reinterpret_cast<const short8*>(&ah[w * 16 + lm][ks + q * 8]);
            short8 afl = *reinterpret_cast<const short8*>(&al[w * 16 + lm][ks + q * 8]);
            #pragma unroll
            for (int nt = 0; nt < 8; nt++) {
                short8 bfh = *reinterpret_cast<const short8*>(&bh[nt * 16 + lm][ks + q * 8]);
                short8 bfl = *reinterpret_cast<const short8*>(&bl[nt * 16 + lm][ks + q * 8]);
                acc[nt] = __builtin_amdgcn_mfma_f32_16x16x32_bf16(afh, bfh, acc[nt], 0, 0, 0);
                acc[nt] = __builtin_amdgcn_mfma_f32_16x16x32_bf16(afh, bfl, acc[nt], 0, 0, 0);
                acc[nt] = __builtin_amdgcn_mfma_f32_16x16x32_bf16(afl, bfh, acc[nt], 0, 0, 0);
            }
        }
        __syncthreads();
    }

    // epilogue: bias, src/dst dots, transpose via LDS -> B-fragment layout
    float s1[4] = {0.f, 0.f, 0.f, 0.f}, s2[4] = {0.f, 0.f, 0.f, 0.f};
    #pragma unroll
    for (int nt = 0; nt < 8; nt++) {
        #pragma unroll
        for (int r = 0; r < 4; r++) {
            float v = acc[nt][r] + bwv[nt];
            s1[r] += v * a1v[nt];
            s2[r] += v * a2v[nt];
            tb[nt * 16 + lm][w * 16 + q * 4 + r] = f2bf(v);   // tb[h][jrel]
        }
    }
    #pragma unroll
    for (int r = 0; r < 4; r++) {
        #pragma unroll
        for (int o = 1; o < 16; o <<= 1) {
            s1[r] += __shfl_xor(s1[r], o);
            s2[r] += __shfl_xor(s2[r], o);
        }
    }
    if (lm == 0) {
        #pragma unroll
        for (int r = 0; r < 4; r++) {
            long row = row0 + w * 16 + q * 4 + r;
            src[row] = (s1[r] + ba0) * LOG2E;   // fold bias-a + log2e (exp -> exp2)
            dst[row] = s2[r] * LOG2E;
        }
    }
    __syncthreads();
    // whF[b][jc][ht][l][e], frag = 512 shorts; block covers jc0..jc0+1
    const int b = (int)(row0 >> 11);
    const int jc0 = (int)((row0 & 2047) >> 5);
    const int f = tid >> 4;          // 0..15: jcrel = f>>3, ht = f&7
    const int sub = tid & 15;
    const int jcrel = f >> 3, ht = f & 7;
    const size_t fbase = (((size_t)b * 64 + jc0 + jcrel) * 8 + ht) * 512;
    #pragma unroll
    for (int i = 0; i < 4; i++) {
        int l = sub * 4 + i;
        uint4 v = *reinterpret_cast<const uint4*>(&tb[ht * 16 + (l & 15)][jcrel * 32 + (l >> 4) * 8]);
        *reinterpret_cast<uint4*>(whF + fbase + l * 8) = v;
    }
}

// ---------------- Kernel 2: merged pack + LDS-staged MFMA attention -------
// 512 blocks (XCD-swizzled) x 256 threads (4 waves). Wave w owns i-rows
// i0+w*16..+15 AND packs those rows' adj, pipelined one 8-chunk group ahead.

#define MD_PRE(PW1, BK, HI)                                                    \
    do {                                                                       \
        md[PW1][0] = maskB[BK][0 + (HI)][wrow];                                \
        md[PW1][1] = maskB[BK][2 + (HI)][wrow];                                \
        md[PW1][2] = maskB[BK][4 + (HI)][wrow];                                \
        md[PW1][3] = maskB[BK][6 + (HI)][wrow];                                \
    } while (0)

#define ADJ_ISSUE(GNEXT, H)                                                    \
    do {                                                                       \
        _Pragma("unroll")                                                      \
        for (int r = 0; r < 8; r++) {                                          \
            const int* ap = adj +                                              \
                (size_t)(rowbase + wave * 16 + (H) * 8 + r) * NDIM +           \
                (GNEXT) * 256 + lane * 4;                                      \
            av[r] = ldnt(ap);                                                  \
        }                                                                      \
    } while (0)

#define ADJ_BALLOT(GNEXT, H)                                                   \
    do {                                                                       \
        _Pragma("unroll")                                                      \
        for (int r = 0; r < 8; r++) {                                          \
            unsigned long long b0 = __ballot(av[r][0] != 0);                   \
            unsigned long long b1 = __ballot(av[r][1] != 0);                   \
            unsigned long long b2 = __ballot(av[r][2] != 0);                   \
            unsigned long long b3 = __ballot(av[r][3] != 0);                   \
            if (lane < 8) {                                                    \
                unsigned long long bb = (lane < 2) ? b0                        \
                                        : (lane < 4) ? b1                      \
                                        : (lane < 6) ? b2 : b3;                \
                unsigned wv = (lane & 1) ? (unsigned)(bb >> 32) : (unsigned)bb;\
                maskB[(GNEXT) & 1][lane][wave * 16 + (H) * 8 + r] = wv;        \
            }                                                                  \
        }                                                                      \
    } while (0)

// Merged chunk C (literal 0..7), T = g8 + C.
// Order: whF issue -> adj duties (counted vmcnt: ballot@C3 waits only the
// 32 adj loads from C0, leaving the newer whF loads in flight) -> dst/md
// prefetch -> weights+MFMA -> write-late -> barrier.
#define CH(C)                                                                  \
    do {                                                                       \
        constexpr int PW = (C) & 1;                                            \
        const int T = g8 + (C);                                                \
        short8 s0, s1;                                                         \
        if (T < 63) { /* issue whF stage loads for chunk T+1 */                \
            const unsigned short* gp = gsrc + (size_t)(T + 1) * 4096;          \
            s0 = *reinterpret_cast<const short8*>(gp);                         \
            s1 = *reinterpret_cast<const short8*>(gp + 512);                   \
        }                                                                      \
        if ((C) == 0 && g8 < 56) ADJ_ISSUE((g8 >> 3) + 1, 0);                  \
        if ((C) == 3 && g8 < 56) {                                             \
            ADJ_BALLOT((g8 >> 3) + 1, 0);                                      \
            ADJ_ISSUE((g8 >> 3) + 1, 1);                                       \
        }                                                                      \
        if ((C) == 6 && g8 < 56) ADJ_BALLOT((g8 >> 3) + 1, 1);                 \
        if (T < 63) { /* dst + mask dword prefetch for T+1 */                  \
            const float* dp = dstp + (T + 1) * 32;                             \
            d[PW ^ 1][0] = *reinterpret_cast<const floatx4*>(dp);              \
            d[PW ^ 1][1] = *reinterpret_cast<const floatx4*>(dp + 4);          \
            if ((C) < 7) {                                                     \
                MD_PRE(PW ^ 1, (g8 >> 3) & 1, (((C) + 1) & 4) ? 1 : 0);        \
            } else {                                                           \
                MD_PRE(PW ^ 1, ((g8 >> 3) + 1) & 1, 0);                        \
            }                                                                  \
        }                                                                      \
        const int base = 8 * ((C) & 3) + 2 * q;                                \
        short8 af;                                                             \
        _Pragma("unroll")                                                      \
        for (int j = 0; j < 8; j++) {                                          \
            float x = si + d[PW][j >> 2][j & 3];                               \
            x = fmaxf(x, 0.01f * x);            /* leaky, scale-invariant */   \
            float e2 = __builtin_amdgcn_exp2f(x);                              \
            unsigned bit = (md[PW][j & 3] >> (base + (j >> 2))) & 1u;          \
            float wgt = bit ? e2 : 0.f;                                        \
            lpart += wgt;                                                      \
            af[j] = (short)f2bf(wgt);                                          \
        }                                                                      \
        _Pragma("unroll")                                                      \
        for (int hj = 0; hj < 8; hj++) {                                       \
            short8 fb = *reinterpret_cast<const short8*>(                      \
                &whS[PW][hj * 512 + lane * 8]);                                \
            acc[hj] = __builtin_amdgcn_mfma_f32_16x16x32_bf16(af, fb,          \
                                                              acc[hj], 0, 0, 0); \
        }                                                                      \
        if (T < 63) { /* write-late: staged whF -> other LDS buffer */         \
            *reinterpret_cast<short8*>(&whS[PW ^ 1][pofs]) = s0;               \
            *reinterpret_cast<short8*>(&whS[PW ^ 1][pofs + 512]) = s1;         \
        }                                                                      \
        __syncthreads();                                                       \
    } while (0)

__global__ __launch_bounds__(256) void k_attn(const int* __restrict__ adj,
                                              const unsigned short* __restrict__ whF,
                                              const float* __restrict__ src,
                                              const float* __restrict__ dst,
                                              float* __restrict__ out) {
    __shared__ short whS[2][4096];       // 16 KB: staged whF chunk dbuf
    __shared__ unsigned maskB[2][8][65]; // 4.1 KB: raw-ballot mask dbuf
                                         // ([65] pad: write banks k+row)
    __shared__ float lred[64];
    __shared__ float linv_s[64];

    const int tid = threadIdx.x;
    // XCD swizzle: 512 blocks, 8 XCDs -> XCD k gets a contiguous 64-block
    // chunk = batches 2k,2k+1. whF working set/XCD: 1 MB (L2-resident).
    const int bid = ((int)blockIdx.x & 7) * 64 + ((int)blockIdx.x >> 3);
    const int b = bid >> 5;                   // 32 i-tiles per batch
    const int i0 = (bid & 31) * 64;
    const int wave = tid >> 6, lane = tid & 63;
    const int lm = lane & 15, q = lane >> 4;
    const int wrow = wave * 16 + lm;          // local i-row this lane owns
    const int rowbase = b * NDIM + i0;

    const float si = src[rowbase + wrow];     // includes ba and log2e scale
    const float* dstp = dst + b * NDIM + q * 8;
    // staging: chunk = 4096 shorts; wave w copies shorts [w*1024, +1024)
    const unsigned short* gsrc =
        whF + (size_t)b * 64 * 8 * 512 + wave * 1024 + lane * 8;
    const int pofs = wave * 1024 + lane * 8;

    floatx4 acc[8];
    #pragma unroll
    for (int hj = 0; hj < 8; hj++) acc[hj] = (floatx4){0.f, 0.f, 0.f, 0.f};
    float lpart = 0.f;

    unsigned md[2][4];      // mask dwords dbuf
    floatx4 d[2][2];        // dst dbuf (L1-hot)
    intx4 av[8];            // adj in-flight rows (8 rows x 256 cols)

    // prologue: stage whF chunk 0; pack group 0 (two drains, amortized);
    // prefetch d slot 0.
    {
        short8 p0 = *reinterpret_cast<const short8*>(gsrc);
        short8 p1 = *reinterpret_cast<const short8*>(gsrc + 512);
        *reinterpret_cast<short8*>(&whS[0][pofs]) = p0;
        *reinterpret_cast<short8*>(&whS[0][pofs + 512]) = p1;
    }
    ADJ_ISSUE(0, 0);
    ADJ_BALLOT(0, 0);
    ADJ_ISSUE(0, 1);
    ADJ_BALLOT(0, 1);
    d[0][0] = *reinterpret_cast<const floatx4*>(dstp);
    d[0][1] = *reinterpret_cast<const floatx4*>(dstp + 4);
    __syncthreads();
    MD_PRE(0, 0, 0);   // chunk 0: bank 0, hi 0

    for (int g8 = 0; g8 < 64; g8 += 8) {
        CH(0); CH(1); CH(2); CH(3);
        CH(4); CH(5); CH(6); CH(7);
    }

    // denominator: combine the 4 q-slices of each row
    lpart += __shfl_xor(lpart, 16);
    lpart += __shfl_xor(lpart, 32);
    if (q == 0) lred[wrow] = lpart;
    __syncthreads();
    if (tid < 64) {
        float l = lred[tid];
        linv_s[tid] = l > 0.f ? 1.f / l : 0.f;
    }
    __syncthreads();

    // epilogue: scale 1/l, ELU, store (C/D: col=lm -> h, row=q*4+r -> i)
    #pragma unroll
    for (int r = 0; r < 4; r++) {
        int il = wave * 16 + q * 4 + r;
        float li = linv_s[il];
        size_t obase = ((size_t)(rowbase + il)) * HDIM + lm;
        #pragma unroll
        for (int hj = 0; hj < 8; hj++) {
            float x = acc[hj][r] * li;
            x = x > 0.f ? x : (__expf(x) - 1.f);
            out[obase + hj * 16] = x;
        }
    }
}

extern "C" void kernel_launch(void* const* d_in, const int* in_sizes, int n_in,
                              void* d_out, int out_size, void* d_ws, size_t ws_size,
                              hipStream_t stream) {
    const float* X  = (const float*)d_in[0];   // [16,2048,256]
    const int* adj  = (const int*)d_in[1];     // [16,2048,2048]
    const float* W  = (const float*)d_in[2];   // [128,256]
    const float* bW = (const float*)d_in[3];   // [128]
    const float* a  = (const float*)d_in[4];   // [1,256]
    const float* ba = (const float*)d_in[5];   // [1]
    float* out = (float*)d_out;                // [16,2048,128]

    float* srcv = (float*)d_ws;                                    // B*N
    float* dstv = srcv + BDIM * NDIM;                              // B*N
    unsigned short* whF = (unsigned short*)(dstv + BDIM * NDIM);   // 8.4 MB bf16 frag-order

    k_wh<<<BDIM * NDIM / 64, 256, 0, stream>>>(X, W, bW, a, ba, srcv, dstv, whF);
    k_attn<<<BDIM * (NDIM / 64), 256, 0, stream>>>(adj, whF, srcv, dstv, out);
}

// Round 9
// 410.611 us; speedup vs baseline: 1.0419x; 1.0076x over previous
//
#include <hip/hip_runtime.h>

// GraphAttentionLayer: B=16, N=2048, F_IN=256, H=128 (fp32 in/out, adj int32)
//  k_wh  : MFMA bf16x3-split GEMM wh = X@W^T + bW; fused src/dst dots
//          (log2e + ba folded); writes wh in MFMA B-FRAGMENT order.
//  k_attn: fused pack+attention, 256 thr / 4 waves, R8 interleave schedule
//          with RAW barriers (R9 change): __syncthreads() emits
//          "s_waitcnt vmcnt(0)" before s_barrier -> drained the adj/whF
//          prefetch queue EVERY chunk, collapsing the software pipeline
//          (R8: 85us, latency-bound). Replaced with
//          {s_waitcnt lgkmcnt(0); s_barrier} -- LDS writes visible, VMEM
//          loads stay in flight across barriers; register-use counted
//          vmcnt orders av/s0/s1 (adj loads ride 3 chunks ~2000cy > HBM).
//          Only cross-wave hazard in loop is whS (LDS) -> lgkmcnt covers.
//          Mask = raw-ballot layout maskB[bank][word][row] (4KB):
//          bit_j of chunk C = ballot_{j&3} >> (8(C&3)+2q+(j>>2)).

#define BDIM 16
#define NDIM 2048
#define FIN 256
#define HDIM 128
#define LOG2E 1.4426950408889634f

typedef short short8 __attribute__((ext_vector_type(8)));
typedef float floatx4 __attribute__((ext_vector_type(4)));
typedef int intx4 __attribute__((ext_vector_type(4)));

__device__ __forceinline__ unsigned short f2bf(float x) {
    unsigned int u = __float_as_uint(x);
    unsigned int r = (u + 0x7fffu + ((u >> 16) & 1u)) >> 16;  // RNE
    return (unsigned short)r;
}
__device__ __forceinline__ float bf2f(unsigned short s) {
    return __uint_as_float(((unsigned int)s) << 16);
}
__device__ __forceinline__ intx4 ldnt(const int* p) {
    return __builtin_nontemporal_load(reinterpret_cast<const intx4*>(p));
}

// ---------------- Kernel 1: wh via MFMA (bf16 hi/lo split) ----------------
// 64 rows x 128 h per block; 4 waves = 4 m-tiles of 16; K in panels of 64.
__global__ __launch_bounds__(256) void k_wh(const float* __restrict__ X,
                                            const float* __restrict__ W,
                                            const float* __restrict__ bW,
                                            const float* __restrict__ a,
                                            const float* __restrict__ ba_p,
                                            float* __restrict__ src,
                                            float* __restrict__ dst,
                                            unsigned short* __restrict__ whF) {
    __shared__ short lds[27648];                    // 54 KB
    short (*ah)[72] = (short(*)[72])lds;
    short (*al)[72] = (short(*)[72])(lds + 4608);
    short (*bh)[72] = (short(*)[72])(lds + 9216);
    short (*bl)[72] = (short(*)[72])(lds + 18432);
    short (*tb)[72] = (short(*)[72])lds;            // epilogue alias [128][72]

    const int tid = threadIdx.x;
    const long row0 = (long)blockIdx.x * 64;
    const int w = tid >> 6, lane = tid & 63;
    const int lm = lane & 15, q = lane >> 4;
    const float ba0 = ba_p[0];

    float a1v[8], a2v[8], bwv[8];
    #pragma unroll
    for (int nt = 0; nt < 8; nt++) {
        a1v[nt] = a[nt * 16 + lm];
        a2v[nt] = a[HDIM + nt * 16 + lm];
        bwv[nt] = bW[nt * 16 + lm];
    }

    floatx4 acc[8];
    #pragma unroll
    for (int nt = 0; nt < 8; nt++) acc[nt] = (floatx4){0.f, 0.f, 0.f, 0.f};

    for (int k0 = 0; k0 < FIN; k0 += 64) {
        #pragma unroll
        for (int u = 0; u < 4; u++) {
            int idx = tid + u * 256;
            int r = idx >> 4, fc = (idx & 15) * 4;
            float4 v = *reinterpret_cast<const float4*>(X + (row0 + r) * FIN + k0 + fc);
            union { unsigned short s[4]; uint2 u2; } ph, pl;
            ph.s[0] = f2bf(v.x); pl.s[0] = f2bf(v.x - bf2f(ph.s[0]));
            ph.s[1] = f2bf(v.y); pl.s[1] = f2bf(v.y - bf2f(ph.s[1]));
            ph.s[2] = f2bf(v.z); pl.s[2] = f2bf(v.z - bf2f(ph.s[2]));
            ph.s[3] = f2bf(v.w); pl.s[3] = f2bf(v.w - bf2f(ph.s[3]));
            *reinterpret_cast<uint2*>(&ah[r][fc]) = ph.u2;
            *reinterpret_cast<uint2*>(&al[r][fc]) = pl.u2;
        }
        #pragma unroll
        for (int u = 0; u < 8; u++) {
            int idx = tid + u * 256;
            int hh = idx >> 4, fc = (idx & 15) * 4;
            float4 v = *reinterpret_cast<const float4*>(W + hh * FIN + k0 + fc);
            union { unsigned short s[4]; uint2 u2; } ph, pl;
            ph.s[0] = f2bf(v.x); pl.s[0] = f2bf(v.x - bf2f(ph.s[0]));
            ph.s[1] = f2bf(v.y); pl.s[1] = f2bf(v.y - bf2f(ph.s[1]));
            ph.s[2] = f2bf(v.z); pl.s[2] = f2bf(v.z - bf2f(ph.s[2]));
            ph.s[3] = f2bf(v.w); pl.s[3] = f2bf(v.w - bf2f(ph.s[3]));
            *reinterpret_cast<uint2*>(&bh[hh][fc]) = ph.u2;
            *reinterpret_cast<uint2*>(&bl[hh][fc]) = pl.u2;
        }
        __syncthreads();
        #pragma unroll
        for (int ks = 0; ks < 64; ks += 32) {
            short8 afh = *reinterpret_cast<const short8*>(&ah[w * 16 + lm][ks + q * 8]);
            short8 afl = *reinterpret_cast<const short8*>(&al[w * 16 + lm][ks + q * 8]);
            #pragma unroll
            for (int nt = 0; nt < 8; nt++) {
                short8 bfh = *reinterpret_cast<const short8*>(&bh[nt * 16 + lm][ks + q * 8]);
                short8 bfl = *reinterpret_cast<const short8*>(&bl[nt * 16 + lm][ks + q * 8]);
                acc[nt] = __builtin_amdgcn_mfma_f32_16x16x32_bf16(afh, bfh, acc[nt], 0, 0, 0);
                acc[nt] = __builtin_amdgcn_mfma_f32_16x16x32_bf16(afh, bfl, acc[nt], 0, 0, 0);
                acc[nt] = __builtin_amdgcn_mfma_f32_16x16x32_bf16(afl, bfh, acc[nt], 0, 0, 0);
            }
        }
        __syncthreads();
    }

    // epilogue: bias, src/dst dots, transpose via LDS -> B-fragment layout
    float s1[4] = {0.f, 0.f, 0.f, 0.f}, s2[4] = {0.f, 0.f, 0.f, 0.f};
    #pragma unroll
    for (int nt = 0; nt < 8; nt++) {
        #pragma unroll
        for (int r = 0; r < 4; r++) {
            float v = acc[nt][r] + bwv[nt];
            s1[r] += v * a1v[nt];
            s2[r] += v * a2v[nt];
            tb[nt * 16 + lm][w * 16 + q * 4 + r] = f2bf(v);   // tb[h][jrel]
        }
    }
    #pragma unroll
    for (int r = 0; r < 4; r++) {
        #pragma unroll
        for (int o = 1; o < 16; o <<= 1) {
            s1[r] += __shfl_xor(s1[r], o);
            s2[r] += __shfl_xor(s2[r], o);
        }
    }
    if (lm == 0) {
        #pragma unroll
        for (int r = 0; r < 4; r++) {
            long row = row0 + w * 16 + q * 4 + r;
            src[row] = (s1[r] + ba0) * LOG2E;   // fold bias-a + log2e (exp -> exp2)
            dst[row] = s2[r] * LOG2E;
        }
    }
    __syncthreads();
    // whF[b][jc][ht][l][e], frag = 512 shorts; block covers jc0..jc0+1
    const int b = (int)(row0 >> 11);
    const int jc0 = (int)((row0 & 2047) >> 5);
    const int f = tid >> 4;          // 0..15: jcrel = f>>3, ht = f&7
    const int sub = tid & 15;
    const int jcrel = f >> 3, ht = f & 7;
    const size_t fbase = (((size_t)b * 64 + jc0 + jcrel) * 8 + ht) * 512;
    #pragma unroll
    for (int i = 0; i < 4; i++) {
        int l = sub * 4 + i;
        uint4 v = *reinterpret_cast<const uint4*>(&tb[ht * 16 + (l & 15)][jcrel * 32 + (l >> 4) * 8]);
        *reinterpret_cast<uint4*>(whF + fbase + l * 8) = v;
    }
}

// ---------------- Kernel 2: merged pack + LDS-staged MFMA attention -------
// 512 blocks (XCD-swizzled) x 256 threads (4 waves). Wave w owns i-rows
// i0+w*16..+15 AND packs those rows' adj, pipelined one 8-chunk group ahead.

// Raw barrier: LDS writes visible (lgkmcnt), VMEM prefetches NOT drained
// (vs __syncthreads' vmcnt(0) drain that killed the R8 pipeline).
#define BAR()                                                                  \
    do {                                                                       \
        asm volatile("s_waitcnt lgkmcnt(0)" ::: "memory");                     \
        __builtin_amdgcn_s_barrier();                                          \
    } while (0)

#define MD_PRE(PW1, BK, HI)                                                    \
    do {                                                                       \
        md[PW1][0] = maskB[BK][0 + (HI)][wrow];                                \
        md[PW1][1] = maskB[BK][2 + (HI)][wrow];                                \
        md[PW1][2] = maskB[BK][4 + (HI)][wrow];                                \
        md[PW1][3] = maskB[BK][6 + (HI)][wrow];                                \
    } while (0)

#define ADJ_ISSUE(GNEXT, H)                                                    \
    do {                                                                       \
        _Pragma("unroll")                                                      \
        for (int r = 0; r < 8; r++) {                                          \
            const int* ap = adj +                                              \
                (size_t)(rowbase + wave * 16 + (H) * 8 + r) * NDIM +           \
                (GNEXT) * 256 + lane * 4;                                      \
            av[r] = ldnt(ap);                                                  \
        }                                                                      \
    } while (0)

#define ADJ_BALLOT(GNEXT, H)                                                   \
    do {                                                                       \
        _Pragma("unroll")                                                      \
        for (int r = 0; r < 8; r++) {                                          \
            unsigned long long b0 = __ballot(av[r][0] != 0);                   \
            unsigned long long b1 = __ballot(av[r][1] != 0);                   \
            unsigned long long b2 = __ballot(av[r][2] != 0);                   \
            unsigned long long b3 = __ballot(av[r][3] != 0);                   \
            if (lane < 8) {                                                    \
                unsigned long long bb = (lane < 2) ? b0                        \
                                        : (lane < 4) ? b1                      \
                                        : (lane < 6) ? b2 : b3;                \
                unsigned wv = (lane & 1) ? (unsigned)(bb >> 32) : (unsigned)bb;\
                maskB[(GNEXT) & 1][lane][wave * 16 + (H) * 8 + r] = wv;        \
            }                                                                  \
        }                                                                      \
    } while (0)

// Merged chunk C (literal 0..7), T = g8 + C.
// Order: whF issue -> adj duties (ballot@C3 takes a COUNTED vmcnt: waits
// only the C0 adj loads, newer whF/dst loads ride on) -> dst/md prefetch
// -> weights+MFMA -> write-late -> raw barrier.
#define CH(C)                                                                  \
    do {                                                                       \
        constexpr int PW = (C) & 1;                                            \
        const int T = g8 + (C);                                                \
        short8 s0, s1;                                                         \
        if (T < 63) { /* issue whF stage loads for chunk T+1 */                \
            const unsigned short* gp = gsrc + (size_t)(T + 1) * 4096;          \
            s0 = *reinterpret_cast<const short8*>(gp);                         \
            s1 = *reinterpret_cast<const short8*>(gp + 512);                   \
        }                                                                      \
        if ((C) == 0 && g8 < 56) ADJ_ISSUE((g8 >> 3) + 1, 0);                  \
        if ((C) == 3 && g8 < 56) {                                             \
            ADJ_BALLOT((g8 >> 3) + 1, 0);                                      \
            ADJ_ISSUE((g8 >> 3) + 1, 1);                                       \
        }                                                                      \
        if ((C) == 6 && g8 < 56) ADJ_BALLOT((g8 >> 3) + 1, 1);                 \
        if (T < 63) { /* dst + mask dword prefetch for T+1 */                  \
            const float* dp = dstp + (T + 1) * 32;                             \
            d[PW ^ 1][0] = *reinterpret_cast<const floatx4*>(dp);              \
            d[PW ^ 1][1] = *reinterpret_cast<const floatx4*>(dp + 4);          \
            if ((C) < 7) {                                                     \
                MD_PRE(PW ^ 1, (g8 >> 3) & 1, (((C) + 1) & 4) ? 1 : 0);        \
            } else {                                                           \
                MD_PRE(PW ^ 1, ((g8 >> 3) + 1) & 1, 0);                        \
            }                                                                  \
        }                                                                      \
        const int base = 8 * ((C) & 3) + 2 * q;                                \
        short8 af;                                                             \
        _Pragma("unroll")                                                      \
        for (int j = 0; j < 8; j++) {                                          \
            float x = si + d[PW][j >> 2][j & 3];                               \
            x = fmaxf(x, 0.01f * x);            /* leaky, scale-invariant */   \
            float e2 = __builtin_amdgcn_exp2f(x);                              \
            unsigned bit = (md[PW][j & 3] >> (base + (j >> 2))) & 1u;          \
            float wgt = bit ? e2 : 0.f;                                        \
            lpart += wgt;                                                      \
            af[j] = (short)f2bf(wgt);                                          \
        }                                                                      \
        _Pragma("unroll")                                                      \
        for (int hj = 0; hj < 8; hj++) {                                       \
            short8 fb = *reinterpret_cast<const short8*>(                      \
                &whS[PW][hj * 512 + lane * 8]);                                \
            acc[hj] = __builtin_amdgcn_mfma_f32_16x16x32_bf16(af, fb,          \
                                                              acc[hj], 0, 0, 0); \
        }                                                                      \
        if (T < 63) { /* write-late: staged whF -> other LDS buffer */         \
            *reinterpret_cast<short8*>(&whS[PW ^ 1][pofs]) = s0;               \
            *reinterpret_cast<short8*>(&whS[PW ^ 1][pofs + 512]) = s1;         \
        }                                                                      \
        BAR();                                                                 \
    } while (0)

__global__ __launch_bounds__(256) void k_attn(const int* __restrict__ adj,
                                              const unsigned short* __restrict__ whF,
                                              const float* __restrict__ src,
                                              const float* __restrict__ dst,
                                              float* __restrict__ out) {
    __shared__ short whS[2][4096];       // 16 KB: staged whF chunk dbuf
    __shared__ unsigned maskB[2][8][65]; // 4.1 KB: raw-ballot mask dbuf
    __shared__ float lred[64];
    __shared__ float linv_s[64];

    const int tid = threadIdx.x;
    // XCD swizzle: 512 blocks, 8 XCDs -> XCD k gets a contiguous 64-block
    // chunk = batches 2k,2k+1. whF working set/XCD: 1 MB (L2-resident).
    const int bid = ((int)blockIdx.x & 7) * 64 + ((int)blockIdx.x >> 3);
    const int b = bid >> 5;                   // 32 i-tiles per batch
    const int i0 = (bid & 31) * 64;
    const int wave = tid >> 6, lane = tid & 63;
    const int lm = lane & 15, q = lane >> 4;
    const int wrow = wave * 16 + lm;          // local i-row this lane owns
    const int rowbase = b * NDIM + i0;

    const float si = src[rowbase + wrow];     // includes ba and log2e scale
    const float* dstp = dst + b * NDIM + q * 8;
    // staging: chunk = 4096 shorts; wave w copies shorts [w*1024, +1024)
    const unsigned short* gsrc =
        whF + (size_t)b * 64 * 8 * 512 + wave * 1024 + lane * 8;
    const int pofs = wave * 1024 + lane * 8;

    floatx4 acc[8];
    #pragma unroll
    for (int hj = 0; hj < 8; hj++) acc[hj] = (floatx4){0.f, 0.f, 0.f, 0.f};
    float lpart = 0.f;

    unsigned md[2][4];      // mask dwords dbuf
    floatx4 d[2][2];        // dst dbuf (L1-hot)
    intx4 av[8];            // adj in-flight rows (8 rows x 256 cols)

    // prologue: stage whF chunk 0; pack group 0 (two drains, amortized);
    // prefetch d slot 0.
    {
        short8 p0 = *reinterpret_cast<const short8*>(gsrc);
        short8 p1 = *reinterpret_cast<const short8*>(gsrc + 512);
        *reinterpret_cast<short8*>(&whS[0][pofs]) = p0;
        *reinterpret_cast<short8*>(&whS[0][pofs + 512]) = p1;
    }
    ADJ_ISSUE(0, 0);
    ADJ_BALLOT(0, 0);
    ADJ_ISSUE(0, 1);
    ADJ_BALLOT(0, 1);
    d[0][0] = *reinterpret_cast<const floatx4*>(dstp);
    d[0][1] = *reinterpret_cast<const floatx4*>(dstp + 4);
    __syncthreads();
    MD_PRE(0, 0, 0);   // chunk 0: bank 0, hi 0

    for (int g8 = 0; g8 < 64; g8 += 8) {
        CH(0); CH(1); CH(2); CH(3);
        CH(4); CH(5); CH(6); CH(7);
    }

    // denominator: combine the 4 q-slices of each row
    lpart += __shfl_xor(lpart, 16);
    lpart += __shfl_xor(lpart, 32);
    if (q == 0) lred[wrow] = lpart;
    __syncthreads();
    if (tid < 64) {
        float l = lred[tid];
        linv_s[tid] = l > 0.f ? 1.f / l : 0.f;
    }
    __syncthreads();

    // epilogue: scale 1/l, ELU, store (C/D: col=lm -> h, row=q*4+r -> i)
    #pragma unroll
    for (int r = 0; r < 4; r++) {
        int il = wave * 16 + q * 4 + r;
        float li = linv_s[il];
        size_t obase = ((size_t)(rowbase + il)) * HDIM + lm;
        #pragma unroll
        for (int hj = 0; hj < 8; hj++) {
            float x = acc[hj][r] * li;
            x = x > 0.f ? x : (__expf(x) - 1.f);
            out[obase + hj * 16] = x;
        }
    }
}

extern "C" void kernel_launch(void* const* d_in, const int* in_sizes, int n_in,
                              void* d_out, int out_size, void* d_ws, size_t ws_size,
                              hipStream_t stream) {
    const float* X  = (const float*)d_in[0];   // [16,2048,256]
    const int* adj  = (const int*)d_in[1];     // [16,2048,2048]
    const float* W  = (const float*)d_in[2];   // [128,256]
    const float* bW = (const float*)d_in[3];   // [128]
    const float* a  = (const float*)d_in[4];   // [1,256]
    const float* ba = (const float*)d_in[5];   // [1]
    float* out = (float*)d_out;                // [16,2048,128]

    float* srcv = (float*)d_ws;                                    // B*N
    float* dstv = srcv + BDIM * NDIM;                              // B*N
    unsigned short* whF = (unsigned short*)(dstv + BDIM * NDIM);   // 8.4 MB bf16 frag-order

    k_wh<<<BDIM * NDIM / 64, 256, 0, stream>>>(X, W, bW, a, ba, srcv, dstv, whF);
    k_attn<<<BDIM * (NDIM / 64), 256, 0, stream>>>(adj, whF, srcv, dstv, out);
}